// Round 2
// baseline (694.446 us; speedup 1.0000x reference)
//
#include <hip/hip_runtime.h>

// grica power-whitening encoder, MI355X.
//   Kp k_prep    : zero C0 accumulator + split Wfc f32 -> bf16 hi/lo
//   K1 k_pass1m  : MFMA split-bf16: y = x@Wfc^T (f32 to d_out) and C0sum += y^T y.
//                  Barrier-free, LDS-free: C-pass fragments are built directly
//                  from accY registers (custom shared k-map — valid since A and
//                  B fragments share it and MFMA k-reduction is a pure sum).
//                  Each wave accumulates its own 32-row slice of full C;
//                  symmetric C: only a<=b sub-tiles computed, mirrored at the
//                  atomicAdd epilogue.
//   K2 k_whiten_ns : W = C^(-1/2) via coupled Newton-Schulz (10 iters).
//                  Reads block-upper-triangular C0sum, symmetrizes on load.
//   K3 k_yw      : d_out = d_out @ W in place (W symmetric).

#define LDS_STRIDE 68    // whiten kernel only
#define NS_ITERS 10

typedef __attribute__((ext_vector_type(8))) short bf16x8;
typedef __attribute__((ext_vector_type(4))) float f32x4;

// split Wfc (64x256 f32) into truncation-split bf16 hi/lo, same layout.
// also zeroes the 64x64 C0 accumulator (first 4096 lanes).
__global__ __launch_bounds__(256) void k_prep(const float* __restrict__ Wfc,
                                              unsigned short* __restrict__ Wh,
                                              unsigned short* __restrict__ Wl,
                                              float* __restrict__ C0sum){
  const int i = blockIdx.x*256 + threadIdx.x;    // grid 64 -> 16384
  if (i < 4096) C0sum[i] = 0.f;
  const float f = Wfc[i];
  const unsigned b  = __float_as_uint(f);
  const unsigned hb = b & 0xFFFF0000u;
  Wh[i] = (unsigned short)(hb >> 16);
  Wl[i] = (unsigned short)(__float_as_uint(f - __uint_as_float(hb)) >> 16);
}

__device__ __forceinline__ void split8(float4 u, float4 v, bf16x8 &hi, bf16x8 &lo){
  const float f[8] = {u.x,u.y,u.z,u.w, v.x,v.y,v.z,v.w};
  #pragma unroll
  for (int i=0;i<8;i++){
    const unsigned b  = __float_as_uint(f[i]);
    const unsigned hb = b & 0xFFFF0000u;
    hi[i] = (short)(hb >> 16);
    lo[i] = (short)(__float_as_uint(f[i] - __uint_as_float(hb)) >> 16);
  }
}

#define MFMA16(a,b,c) __builtin_amdgcn_mfma_f32_16x16x32_bf16((a),(b),(c),0,0,0)

__global__ __launch_bounds__(256,3) void k_pass1m(const float* __restrict__ x,
                                                  const unsigned short* __restrict__ Wh,
                                                  const unsigned short* __restrict__ Wl,
                                                  float* __restrict__ C0sum,
                                                  float* __restrict__ y,
                                                  int N, int ntiles){
  const int t  = threadIdx.x;
  const int wv = t>>6, l = t&63;
  const int lg = l>>4, lr = l&15;

  // symmetric C accumulators: pairs (a,b), a<=b: 10 tiles of 16x16
  f32x4 accC[10];
  #pragma unroll
  for (int p=0;p<10;p++) accC[p] = (f32x4){0.f,0.f,0.f,0.f};

  for (int tile = blockIdx.x; tile < ntiles; tile += gridDim.x){
    const long r0 = (long)tile*128;

    // ---- y-GEMM: 128x64 tile, wave wv owns rows [32wv, 32wv+32)
    f32x4 accY[2][4];
    #pragma unroll
    for (int rb=0;rb<2;rb++)
      #pragma unroll
      for (int cb=0;cb<4;cb++) accY[rb][cb] = (f32x4){0.f,0.f,0.f,0.f};

    #pragma unroll 1
    for (int ks=0; ks<8; ++ks){
      const int kl = 32*ks + 8*lg;                 // lane's 8 consecutive k
      bf16x8 ahi[2], alo[2];
      #pragma unroll
      for (int rb=0; rb<2; ++rb){
        const long row = r0 + 32*wv + 16*rb + lr;  // A row = lane&15
        float4 a0, a1;
        if (row < (long)N){
          a0 = *(const float4*)&x[row*256 + kl];
          a1 = *(const float4*)&x[row*256 + kl + 4];
        } else {
          a0 = make_float4(0.f,0.f,0.f,0.f);
          a1 = make_float4(0.f,0.f,0.f,0.f);
        }
        split8(a0, a1, ahi[rb], alo[rb]);
      }
      #pragma unroll
      for (int cb=0; cb<4; ++cb){
        const bf16x8 bhi = *(const bf16x8*)&Wh[(16*cb+lr)*256 + kl];
        const bf16x8 blo = *(const bf16x8*)&Wl[(16*cb+lr)*256 + kl];
        #pragma unroll
        for (int rb=0; rb<2; ++rb){
          accY[rb][cb] = MFMA16(ahi[rb], bhi, accY[rb][cb]);
          accY[rb][cb] = MFMA16(alo[rb], bhi, accY[rb][cb]);
          accY[rb][cb] = MFMA16(ahi[rb], blo, accY[rb][cb]);
        }
      }
    }

    // ---- epilogue 1: y -> global f32
    // C/D layout (m89-verified): col = lane&15, row = 4*(lane>>4)+i
    #pragma unroll
    for (int rb=0; rb<2; ++rb){
      #pragma unroll
      for (int cb=0; cb<4; ++cb){
        #pragma unroll
        for (int i=0;i<4;i++){
          const long row = r0 + 32*wv + 16*rb + 4*lg + i;
          if (row < (long)N) y[row*64 + 16*cb + lr] = accY[rb][cb][i];
        }
      }
    }

    // ---- epilogue 2: in-register C contribution (K=32 = this wave's rows).
    // k-slot j of lane (lg,lr) := tile-local row 16*(j>>2)+4*lg+(j&3).
    // Valid k-map: A and B fragments share it; MFMA k-reduction is a pure sum.
    // frag for col-group g: els {accY[0][g][0..3], accY[1][g][0..3]}.
    bf16x8 chi[4], clo[4];
    #pragma unroll
    for (int g=0; g<4; ++g){
      const float4 u = make_float4(accY[0][g][0],accY[0][g][1],accY[0][g][2],accY[0][g][3]);
      const float4 v = make_float4(accY[1][g][0],accY[1][g][1],accY[1][g][2],accY[1][g][3]);
      split8(u, v, chi[g], clo[g]);
    }
    {
      int p = 0;
      #pragma unroll
      for (int a=0; a<4; ++a){
        #pragma unroll
        for (int b=a; b<4; ++b){
          accC[p] = MFMA16(chi[a], chi[b], accC[p]);
          accC[p] = MFMA16(clo[a], chi[b], accC[p]);
          accC[p] = MFMA16(chi[a], clo[b], accC[p]);
          ++p;
        }
      }
    }
  }

  // ---- final: atomic-accumulate symmetric C (mirror off-diagonal tiles)
  {
    int p = 0;
    #pragma unroll
    for (int a=0; a<4; ++a){
      #pragma unroll
      for (int b=a; b<4; ++b){
        #pragma unroll
        for (int i=0;i<4;i++){
          const int m = 16*a + 4*lg + i;
          const int n = 16*b + lr;
          atomicAdd(&C0sum[m*64 + n], accC[p][i]);
          if (a != b)
            atomicAdd(&C0sum[n*64 + m], accC[p][i]);
        }
        ++p;
      }
    }
  }
}

#define WMAXRED(s) { s=fmaxf(s,__shfl_xor(s,32)); s=fmaxf(s,__shfl_xor(s,16)); \
  s=fmaxf(s,__shfl_xor(s,8)); s=fmaxf(s,__shfl_xor(s,4)); \
  s=fmaxf(s,__shfl_xor(s,2)); s=fmaxf(s,__shfl_xor(s,1)); }

// Coupled Newton-Schulz for C^(-1/2): A=C/tau (Gershgorin tau), Y=A, Z=I;
// T = 1.5I-0.5ZY; Y<-YT; Z<-TZ;  Z -> A^(-1/2);  W = Z/sqrt(tau).
// C0sum is block-upper-triangular (16x16 tiles, col-tile >= row-tile filled);
// symmetrize on load.
__global__ __launch_bounds__(256,1) void k_whiten_ns(const float* __restrict__ C0sum,
                                                     float* __restrict__ Wout,
                                                     float invN){
  __shared__ __align__(16) float B0[64*LDS_STRIDE];
  __shared__ __align__(16) float B1[64*LDS_STRIDE];
  __shared__ __align__(16) float B2[64*LDS_STRIDE];
  __shared__ __align__(16) float B3[64*LDS_STRIDE];
  __shared__ float sred[8];

  const int t = threadIdx.x;
  const int w = t>>6, l = t&63;
  const int di = t>>2, djb = (t&3)*16;
  const int rg = l&3, cg = l>>2;
  const int row0 = 16*w + 4*rg;

  // thread's 16 cols live in col-tile (t&3); row-tile = di>>4.
  const bool upper = ((t&3) >= (di>>4));
  float4 cv[4];
  float psum = 0.f;
  #pragma unroll
  for (int c=0;c<4;c++){
    if (upper){
      cv[c] = *(const float4*)&C0sum[di*64 + djb + 4*c];
    } else {
      const int j0 = djb + 4*c;
      cv[c] = make_float4(C0sum[(j0+0)*64 + di], C0sum[(j0+1)*64 + di],
                          C0sum[(j0+2)*64 + di], C0sum[(j0+3)*64 + di]);
    }
    psum += fabsf(cv[c].x)+fabsf(cv[c].y)+fabsf(cv[c].z)+fabsf(cv[c].w);
  }
  psum *= invN;
  psum += __shfl_xor(psum,1);
  psum += __shfl_xor(psum,2);
  float m = psum;
  WMAXRED(m);
  if (l==0) sred[w] = m;
  __syncthreads();
  const float tau = fmaxf(fmaxf(sred[0],sred[1]), fmaxf(sred[2],sred[3]));
  const float sA = invN/tau;

  #pragma unroll
  for (int c=0;c<4;c++){
    float4 v4 = cv[c];
    v4.x*=sA; v4.y*=sA; v4.z*=sA; v4.w*=sA;
    *(float4*)&B0[di*LDS_STRIDE + djb + 4*c] = v4;
    const int j0 = djb + 4*c;
    *(float4*)&B1[di*LDS_STRIDE + j0] = make_float4(
        (di==j0+0)?1.f:0.f, (di==j0+1)?1.f:0.f,
        (di==j0+2)?1.f:0.f, (di==j0+3)?1.f:0.f);
  }
  __syncthreads();

  float *pY=B0, *pZ=B1, *pT=B2, *pU=B3;

  auto mm = [&](float* __restrict__ D, const float* __restrict__ A,
                const float* __restrict__ Bm, bool isT){
    float acc[4][4];
    #pragma unroll
    for (int i=0;i<4;i++)
      #pragma unroll
      for (int j=0;j<4;j++) acc[i][j] = 0.f;
    #pragma unroll 1
    for (int c=0;c<4;c++){
      float arr[4][16];
      #pragma unroll
      for (int ri=0;ri<4;ri++)
        #pragma unroll
        for (int k4=0;k4<4;k4++){
          const float4 a4 = *(const float4*)&A[(row0+ri)*LDS_STRIDE + 16*c + 4*k4];
          arr[ri][4*k4+0]=a4.x; arr[ri][4*k4+1]=a4.y;
          arr[ri][4*k4+2]=a4.z; arr[ri][4*k4+3]=a4.w;
        }
      #pragma unroll
      for (int kk=0;kk<16;kk++){
        const float4 b = *(const float4*)&Bm[(16*c+kk)*LDS_STRIDE + 4*cg];
        #pragma unroll
        for (int ri=0;ri<4;ri++){
          acc[ri][0] += arr[ri][kk]*b.x;
          acc[ri][1] += arr[ri][kk]*b.y;
          acc[ri][2] += arr[ri][kk]*b.z;
          acc[ri][3] += arr[ri][kk]*b.w;
        }
      }
    }
    if (isT){
      #pragma unroll
      for (int ri=0;ri<4;ri++)
        #pragma unroll
        for (int j=0;j<4;j++)
          acc[ri][j] = -0.5f*acc[ri][j] + ((row0+ri == 4*cg+j) ? 1.5f : 0.f);
    }
    #pragma unroll
    for (int ri=0;ri<4;ri++)
      *(float4*)&D[(row0+ri)*LDS_STRIDE + 4*cg] =
          make_float4(acc[ri][0],acc[ri][1],acc[ri][2],acc[ri][3]);
    __syncthreads();
  };

  #pragma unroll 1
  for (int it=0; it<NS_ITERS; ++it){
    mm(pT, pZ, pY, true);
    if (it < NS_ITERS-1) mm(pU, pY, pT, false);
    mm(pY, pT, pZ, false);
    float* oY=pY; float* oZ=pZ; float* oU=pU;
    pY = oU; pZ = oY; pU = oZ;
  }

  const float fs = rsqrtf(tau);
  #pragma unroll
  for (int c=0;c<4;c++){
    float4 z4 = *(const float4*)&pZ[di*LDS_STRIDE + djb + 4*c];
    z4.x*=fs; z4.y*=fs; z4.z*=fs; z4.w*=fs;
    *(float4*)&Wout[di*64 + djb + 4*c] = z4;
  }
}

// In-place: yio[r][:] <- yio[r][:] @ W  (W symmetric 64x64 in LDS).
// Wl is read-only after the one-time staging: no loop barriers needed.
__global__ __launch_bounds__(256) void k_yw(float* __restrict__ yio,
                                            const float* __restrict__ Wsym,
                                            int N, int ntiles){
  __shared__ __align__(16) float Wl[64*64];
  const int t = threadIdx.x;
  #pragma unroll
  for (int q=0;q<16;q++) Wl[q*256+t] = Wsym[q*256+t];
  __syncthreads();
  const int rowg = t>>4, cg = t&15;

  for (int tile = blockIdx.x; tile < ntiles; tile += gridDim.x){
    const long r0 = (long)tile*64;
    const float* yp[4]; bool rv[4]; long rw[4];
    #pragma unroll
    for (int ri=0;ri<4;ri++){
      const long r = r0 + rowg*4 + ri;
      rv[ri] = (r < (long)N);
      const long rc = rv[ri] ? r : (long)N-1;
      yp[ri] = yio + rc*64;
      rw[ri] = rc*64;
    }
    float acc[4][4];
    #pragma unroll
    for (int ri=0;ri<4;ri++){ acc[ri][0]=0.f; acc[ri][1]=0.f; acc[ri][2]=0.f; acc[ri][3]=0.f; }
    #pragma unroll 4
    for (int ks=0;ks<16;ks++){
      const int k = 4*ks;
      const float4 b0 = *(const float4*)&Wl[(k+0)*64 + 4*cg];
      const float4 b1 = *(const float4*)&Wl[(k+1)*64 + 4*cg];
      const float4 b2 = *(const float4*)&Wl[(k+2)*64 + 4*cg];
      const float4 b3 = *(const float4*)&Wl[(k+3)*64 + 4*cg];
      #pragma unroll
      for (int ri=0;ri<4;ri++){
        const float4 a = *(const float4*)&yp[ri][k];
        acc[ri][0] += a.x*b0.x + a.y*b1.x + a.z*b2.x + a.w*b3.x;
        acc[ri][1] += a.x*b0.y + a.y*b1.y + a.z*b2.y + a.w*b3.y;
        acc[ri][2] += a.x*b0.z + a.y*b1.z + a.z*b2.z + a.w*b3.z;
        acc[ri][3] += a.x*b0.w + a.y*b1.w + a.z*b2.w + a.w*b3.w;
      }
    }
    #pragma unroll
    for (int ri=0;ri<4;ri++)
      if (rv[ri])
        *(float4*)&yio[rw[ri] + 4*cg] =
            make_float4(acc[ri][0],acc[ri][1],acc[ri][2],acc[ri][3]);
  }
}

extern "C" void kernel_launch(void* const* d_in, const int* in_sizes, int n_in,
                              void* d_out, int out_size, void* d_ws, size_t ws_size,
                              hipStream_t stream) {
  const float* x   = (const float*)d_in[0];   // [N,256]
  const float* Wfc = (const float*)d_in[1];   // [64,256]
  const float* R   = (const float*)d_in[2];   // unused: W = C^-1/2 exactly
  float* out = (float*)d_out;                 // [N,64] (holds y, then out)
  char*  ws  = (char*)d_ws;
  (void)R;

  float*          C0sum = (float*)(ws + 0);          // 16 KB
  float*          Wsym  = (float*)(ws + 16384);      // 16 KB
  unsigned short* Wh    = (unsigned short*)(ws + 32768);  // 32 KB
  unsigned short* Wlo   = (unsigned short*)(ws + 65536);  // 32 KB

  const int N = in_sizes[0] / 256;
  const int nt1 = (N + 127)/128;
  const int nt2 = (N + 63)/64;

  k_prep     <<<64,   256, 0, stream>>>(Wfc, Wh, Wlo, C0sum);
  k_pass1m   <<<1024, 256, 0, stream>>>(x, Wh, Wlo, C0sum, out, N, nt1);
  k_whiten_ns<<<1,    256, 0, stream>>>(C0sum, Wsym, 1.0f/(float)N);
  k_yw       <<<2048, 256, 0, stream>>>(out, Wsym, N, nt2);
}

// Round 3
// 440.279 us; speedup vs baseline: 1.5773x; 1.5773x over previous
//
#include <hip/hip_runtime.h>

// grica power-whitening encoder, MI355X.
//   Kp k_prep    : zero C0 accumulator + split Wfc f32 -> bf16 hi/lo
//   K1 k_ygemm   : pure streaming MFMA split-bf16 GEMM y = x@Wfc^T.
//                  Barrier-free, LDS-free, one 128-row tile per block.
//   K2 k_cov     : C0sum = y^T y via MFMA, reading y (L3-hot) directly from
//                  global with the shared-k-map trick; per-wave register
//                  accumulation over tiles, one atomicAdd set per block.
//   K3 k_whiten_ns : W = C^(-1/2) via coupled Newton-Schulz (10 iters).
//   K4 k_yw      : d_out = d_out @ W in place (W symmetric).

#define LDS_STRIDE 68    // whiten kernel only
#define NS_ITERS 10

typedef __attribute__((ext_vector_type(8))) short bf16x8;
typedef __attribute__((ext_vector_type(4))) float f32x4;

// split Wfc (64x256 f32) into truncation-split bf16 hi/lo, same layout.
// also zeroes the 64x64 C0 accumulator (first 4096 lanes).
__global__ __launch_bounds__(256) void k_prep(const float* __restrict__ Wfc,
                                              unsigned short* __restrict__ Wh,
                                              unsigned short* __restrict__ Wl,
                                              float* __restrict__ C0sum){
  const int i = blockIdx.x*256 + threadIdx.x;    // grid 64 -> 16384
  if (i < 4096) C0sum[i] = 0.f;
  const float f = Wfc[i];
  const unsigned b  = __float_as_uint(f);
  const unsigned hb = b & 0xFFFF0000u;
  Wh[i] = (unsigned short)(hb >> 16);
  Wl[i] = (unsigned short)(__float_as_uint(f - __uint_as_float(hb)) >> 16);
}

__device__ __forceinline__ void split8(float4 u, float4 v, bf16x8 &hi, bf16x8 &lo){
  const float f[8] = {u.x,u.y,u.z,u.w, v.x,v.y,v.z,v.w};
  #pragma unroll
  for (int i=0;i<8;i++){
    const unsigned b  = __float_as_uint(f[i]);
    const unsigned hb = b & 0xFFFF0000u;
    hi[i] = (short)(hb >> 16);
    lo[i] = (short)(__float_as_uint(f[i] - __uint_as_float(hb)) >> 16);
  }
}

#define MFMA16(a,b,c) __builtin_amdgcn_mfma_f32_16x16x32_bf16((a),(b),(c),0,0,0)

// Pure y = x @ Wfc^T. One 128x64 tile per block, wave wv owns 32 rows.
__global__ __launch_bounds__(256,4) void k_ygemm(const float* __restrict__ x,
                                                 const unsigned short* __restrict__ Wh,
                                                 const unsigned short* __restrict__ Wl,
                                                 float* __restrict__ y,
                                                 int N){
  const int t  = threadIdx.x;
  const int wv = t>>6, l = t&63;
  const int lg = l>>4, lr = l&15;
  const long r0 = (long)blockIdx.x*128;

  f32x4 accY[2][4];
  #pragma unroll
  for (int rb=0;rb<2;rb++)
    #pragma unroll
    for (int cb=0;cb<4;cb++) accY[rb][cb] = (f32x4){0.f,0.f,0.f,0.f};

  #pragma unroll 2
  for (int ks=0; ks<8; ++ks){
    const int kl = 32*ks + 8*lg;                 // lane's 8 consecutive k
    bf16x8 ahi[2], alo[2];
    #pragma unroll
    for (int rb=0; rb<2; ++rb){
      const long row = r0 + 32*wv + 16*rb + lr;  // A row = lane&15
      float4 a0, a1;
      if (row < (long)N){
        a0 = *(const float4*)&x[row*256 + kl];
        a1 = *(const float4*)&x[row*256 + kl + 4];
      } else {
        a0 = make_float4(0.f,0.f,0.f,0.f);
        a1 = make_float4(0.f,0.f,0.f,0.f);
      }
      split8(a0, a1, ahi[rb], alo[rb]);
    }
    #pragma unroll
    for (int cb=0; cb<4; ++cb){
      const bf16x8 bhi = *(const bf16x8*)&Wh[(16*cb+lr)*256 + kl];
      const bf16x8 blo = *(const bf16x8*)&Wl[(16*cb+lr)*256 + kl];
      #pragma unroll
      for (int rb=0; rb<2; ++rb){
        accY[rb][cb] = MFMA16(ahi[rb], bhi, accY[rb][cb]);
        accY[rb][cb] = MFMA16(alo[rb], bhi, accY[rb][cb]);
        accY[rb][cb] = MFMA16(ahi[rb], blo, accY[rb][cb]);
      }
    }
  }

  // C/D layout (m89-verified): col = lane&15, row = 4*(lane>>4)+i
  #pragma unroll
  for (int rb=0; rb<2; ++rb){
    #pragma unroll
    for (int cb=0; cb<4; ++cb){
      #pragma unroll
      for (int i=0;i<4;i++){
        const long row = r0 + 32*wv + 16*rb + 4*lg + i;
        if (row < (long)N) y[row*64 + 16*cb + lr] = accY[rb][cb][i];
      }
    }
  }
}

// C0sum += y^T y. y read directly from global (L3-hot, 64B lines fully used).
// Shared k-map: k-slot j of lane (lg,lr) := row 32*ks+8*lg+j of the tile.
// Valid since A and B fragments share the map and MFMA k-reduction is a sum.
__global__ __launch_bounds__(256,4) void k_cov(const float* __restrict__ y,
                                               float* __restrict__ C0sum,
                                               int N, int ntiles){
  const int t  = threadIdx.x;
  const int wv = t>>6, l = t&63;
  const int lg = l>>4, lr = l&15;

  f32x4 accC[4];
  #pragma unroll
  for (int b=0;b<4;b++) accC[b] = (f32x4){0.f,0.f,0.f,0.f};

  for (int tile = blockIdx.x; tile < ntiles; tile += gridDim.x){
    const long r0 = (long)tile*128;
    #pragma unroll 1
    for (int ks=0; ks<4; ++ks){
      bf16x8 fhi[4], flo[4];
      bf16x8 ahi, alo;
      #pragma unroll
      for (int b=0;b<4;b++){
        float v[8];
        #pragma unroll
        for (int j=0;j<8;j++){
          const long row = r0 + 32*ks + 8*lg + j;
          v[j] = (row < (long)N) ? y[row*64 + 16*b + lr] : 0.f;
        }
        bf16x8 h, lo;
        split8(make_float4(v[0],v[1],v[2],v[3]),
               make_float4(v[4],v[5],v[6],v[7]), h, lo);
        fhi[b] = h; flo[b] = lo;
        if (b == wv){ ahi = h; alo = lo; }   // A-frag = this wave's row-block col-slice
      }
      #pragma unroll
      for (int b=0;b<4;b++){
        accC[b] = MFMA16(ahi, fhi[b], accC[b]);
        accC[b] = MFMA16(alo, fhi[b], accC[b]);
        accC[b] = MFMA16(ahi, flo[b], accC[b]);
      }
    }
  }

  // D layout: row (A-dim) = 4*lg+i, col (B-dim) = lr within the (wv,b) tile.
  #pragma unroll
  for (int b=0;b<4;b++)
    #pragma unroll
    for (int i=0;i<4;i++){
      const int m = 16*wv + 4*lg + i;
      const int n = 16*b + lr;
      atomicAdd(&C0sum[m*64 + n], accC[b][i]);
    }
}

#define WMAXRED(s) { s=fmaxf(s,__shfl_xor(s,32)); s=fmaxf(s,__shfl_xor(s,16)); \
  s=fmaxf(s,__shfl_xor(s,8)); s=fmaxf(s,__shfl_xor(s,4)); \
  s=fmaxf(s,__shfl_xor(s,2)); s=fmaxf(s,__shfl_xor(s,1)); }

// Coupled Newton-Schulz for C^(-1/2): A=C/tau (Gershgorin tau), Y=A, Z=I;
// T = 1.5I-0.5ZY; Y<-YT; Z<-TZ;  Z -> A^(-1/2);  W = Z/sqrt(tau).
__global__ __launch_bounds__(256,1) void k_whiten_ns(const float* __restrict__ C0sum,
                                                     float* __restrict__ Wout,
                                                     float invN){
  __shared__ __align__(16) float B0[64*LDS_STRIDE];
  __shared__ __align__(16) float B1[64*LDS_STRIDE];
  __shared__ __align__(16) float B2[64*LDS_STRIDE];
  __shared__ __align__(16) float B3[64*LDS_STRIDE];
  __shared__ float sred[8];

  const int t = threadIdx.x;
  const int w = t>>6, l = t&63;
  const int di = t>>2, djb = (t&3)*16;
  const int rg = l&3, cg = l>>2;
  const int row0 = 16*w + 4*rg;

  float4 cv[4];
  float psum = 0.f;
  #pragma unroll
  for (int c=0;c<4;c++){
    cv[c] = *(const float4*)&C0sum[di*64 + djb + 4*c];
    psum += fabsf(cv[c].x)+fabsf(cv[c].y)+fabsf(cv[c].z)+fabsf(cv[c].w);
  }
  psum *= invN;
  psum += __shfl_xor(psum,1);
  psum += __shfl_xor(psum,2);
  float m = psum;
  WMAXRED(m);
  if (l==0) sred[w] = m;
  __syncthreads();
  const float tau = fmaxf(fmaxf(sred[0],sred[1]), fmaxf(sred[2],sred[3]));
  const float sA = invN/tau;

  #pragma unroll
  for (int c=0;c<4;c++){
    float4 v4 = cv[c];
    v4.x*=sA; v4.y*=sA; v4.z*=sA; v4.w*=sA;
    *(float4*)&B0[di*LDS_STRIDE + djb + 4*c] = v4;
    const int j0 = djb + 4*c;
    *(float4*)&B1[di*LDS_STRIDE + j0] = make_float4(
        (di==j0+0)?1.f:0.f, (di==j0+1)?1.f:0.f,
        (di==j0+2)?1.f:0.f, (di==j0+3)?1.f:0.f);
  }
  __syncthreads();

  float *pY=B0, *pZ=B1, *pT=B2, *pU=B3;

  auto mm = [&](float* __restrict__ D, const float* __restrict__ A,
                const float* __restrict__ Bm, bool isT){
    float acc[4][4];
    #pragma unroll
    for (int i=0;i<4;i++)
      #pragma unroll
      for (int j=0;j<4;j++) acc[i][j] = 0.f;
    #pragma unroll 1
    for (int c=0;c<4;c++){
      float arr[4][16];
      #pragma unroll
      for (int ri=0;ri<4;ri++)
        #pragma unroll
        for (int k4=0;k4<4;k4++){
          const float4 a4 = *(const float4*)&A[(row0+ri)*LDS_STRIDE + 16*c + 4*k4];
          arr[ri][4*k4+0]=a4.x; arr[ri][4*k4+1]=a4.y;
          arr[ri][4*k4+2]=a4.z; arr[ri][4*k4+3]=a4.w;
        }
      #pragma unroll
      for (int kk=0;kk<16;kk++){
        const float4 b = *(const float4*)&Bm[(16*c+kk)*LDS_STRIDE + 4*cg];
        #pragma unroll
        for (int ri=0;ri<4;ri++){
          acc[ri][0] += arr[ri][kk]*b.x;
          acc[ri][1] += arr[ri][kk]*b.y;
          acc[ri][2] += arr[ri][kk]*b.z;
          acc[ri][3] += arr[ri][kk]*b.w;
        }
      }
    }
    if (isT){
      #pragma unroll
      for (int ri=0;ri<4;ri++)
        #pragma unroll
        for (int j=0;j<4;j++)
          acc[ri][j] = -0.5f*acc[ri][j] + ((row0+ri == 4*cg+j) ? 1.5f : 0.f);
    }
    #pragma unroll
    for (int ri=0;ri<4;ri++)
      *(float4*)&D[(row0+ri)*LDS_STRIDE + 4*cg] =
          make_float4(acc[ri][0],acc[ri][1],acc[ri][2],acc[ri][3]);
    __syncthreads();
  };

  #pragma unroll 1
  for (int it=0; it<NS_ITERS; ++it){
    mm(pT, pZ, pY, true);
    if (it < NS_ITERS-1) mm(pU, pY, pT, false);
    mm(pY, pT, pZ, false);
    float* oY=pY; float* oZ=pZ; float* oU=pU;
    pY = oU; pZ = oY; pU = oZ;
  }

  const float fs = rsqrtf(tau);
  #pragma unroll
  for (int c=0;c<4;c++){
    float4 z4 = *(const float4*)&pZ[di*LDS_STRIDE + djb + 4*c];
    z4.x*=fs; z4.y*=fs; z4.z*=fs; z4.w*=fs;
    *(float4*)&Wout[di*64 + djb + 4*c] = z4;
  }
}

// In-place: yio[r][:] <- yio[r][:] @ W  (W symmetric 64x64 in LDS).
// Wl is read-only after the one-time staging: no loop barriers needed.
__global__ __launch_bounds__(256) void k_yw(float* __restrict__ yio,
                                            const float* __restrict__ Wsym,
                                            int N, int ntiles){
  __shared__ __align__(16) float Wl[64*64];
  const int t = threadIdx.x;
  #pragma unroll
  for (int q=0;q<16;q++) Wl[q*256+t] = Wsym[q*256+t];
  __syncthreads();
  const int rowg = t>>4, cg = t&15;

  for (int tile = blockIdx.x; tile < ntiles; tile += gridDim.x){
    const long r0 = (long)tile*64;
    const float* yp[4]; bool rv[4]; long rw[4];
    #pragma unroll
    for (int ri=0;ri<4;ri++){
      const long r = r0 + rowg*4 + ri;
      rv[ri] = (r < (long)N);
      const long rc = rv[ri] ? r : (long)N-1;
      yp[ri] = yio + rc*64;
      rw[ri] = rc*64;
    }
    float acc[4][4];
    #pragma unroll
    for (int ri=0;ri<4;ri++){ acc[ri][0]=0.f; acc[ri][1]=0.f; acc[ri][2]=0.f; acc[ri][3]=0.f; }
    #pragma unroll 4
    for (int ks=0;ks<16;ks++){
      const int k = 4*ks;
      const float4 b0 = *(const float4*)&Wl[(k+0)*64 + 4*cg];
      const float4 b1 = *(const float4*)&Wl[(k+1)*64 + 4*cg];
      const float4 b2 = *(const float4*)&Wl[(k+2)*64 + 4*cg];
      const float4 b3 = *(const float4*)&Wl[(k+3)*64 + 4*cg];
      #pragma unroll
      for (int ri=0;ri<4;ri++){
        const float4 a = *(const float4*)&yp[ri][k];
        acc[ri][0] += a.x*b0.x + a.y*b1.x + a.z*b2.x + a.w*b3.x;
        acc[ri][1] += a.x*b0.y + a.y*b1.y + a.z*b2.y + a.w*b3.y;
        acc[ri][2] += a.x*b0.z + a.y*b1.z + a.z*b2.z + a.w*b3.z;
        acc[ri][3] += a.x*b0.w + a.y*b1.w + a.z*b2.w + a.w*b3.w;
      }
    }
    #pragma unroll
    for (int ri=0;ri<4;ri++)
      if (rv[ri])
        *(float4*)&yio[rw[ri] + 4*cg] =
            make_float4(acc[ri][0],acc[ri][1],acc[ri][2],acc[ri][3]);
  }
}

extern "C" void kernel_launch(void* const* d_in, const int* in_sizes, int n_in,
                              void* d_out, int out_size, void* d_ws, size_t ws_size,
                              hipStream_t stream) {
  const float* x   = (const float*)d_in[0];   // [N,256]
  const float* Wfc = (const float*)d_in[1];   // [64,256]
  const float* R   = (const float*)d_in[2];   // unused: W = C^-1/2 exactly
  float* out = (float*)d_out;                 // [N,64] (holds y, then out)
  char*  ws  = (char*)d_ws;
  (void)R;

  float*          C0sum = (float*)(ws + 0);          // 16 KB
  float*          Wsym  = (float*)(ws + 16384);      // 16 KB
  unsigned short* Wh    = (unsigned short*)(ws + 32768);  // 32 KB
  unsigned short* Wlo   = (unsigned short*)(ws + 65536);  // 32 KB

  const int N = in_sizes[0] / 256;
  const int nt1 = (N + 127)/128;
  const int nt2 = (N + 63)/64;

  k_prep     <<<64,   256, 0, stream>>>(Wfc, Wh, Wlo, C0sum);
  k_ygemm    <<<nt1,  256, 0, stream>>>(x, Wh, Wlo, out, N);
  k_cov      <<<512,  256, 0, stream>>>(out, C0sum, N, nt1);
  k_whiten_ns<<<1,    256, 0, stream>>>(C0sum, Wsym, 1.0f/(float)N);
  k_yw       <<<2048, 256, 0, stream>>>(out, Wsym, N, nt2);
}